// Round 8
// baseline (161.680 us; speedup 1.0000x reference)
//
#include <hip/hip_runtime.h>
#include <hip/hip_bf16.h>
#include <cstdint>

#define N_IDE 4096
#define M_U   16384
#define D_DIM 256
#define EPSF  1e-12f
#define INV_M (1.0f / 16384.0f)

typedef _Float16 f16x8 __attribute__((ext_vector_type(8)));
typedef float    f32x4 __attribute__((ext_vector_type(4)));

// ---- async global->LDS 16B copy. LDS dest = wave-uniform base + lane*16. ----
__device__ __forceinline__ void gll16(const void* g, void* l) {
  __builtin_amdgcn_global_load_lds(
      (const __attribute__((address_space(1))) void*)(uintptr_t)g,
      (__attribute__((address_space(3))) void*)(uint32_t)(uintptr_t)l,
      16, 0, 0);
}

__device__ __forceinline__ unsigned short f2h_bits(float f) {
  _Float16 h = (_Float16)f;
  return __builtin_bit_cast(unsigned short, h);
}

// ---- Kernel 1: fp32 -> f16 convert + row squared-norms (one wave per row) ----
__global__ __launch_bounds__(256) void k_conv(const float* __restrict__ ide,
                                              const float* __restrict__ u,
                                              unsigned short* __restrict__ Ah,
                                              unsigned short* __restrict__ Bh,
                                              float* __restrict__ x2,
                                              float* __restrict__ y2,
                                              float* __restrict__ out) {
  if (blockIdx.x == 0 && threadIdx.x == 0) out[0] = 0.f;   // replaces memset launch
  int gw = (blockIdx.x * 256 + threadIdx.x) >> 6;
  int l  = threadIdx.x & 63;
  const float4* src;
  ushort4* dst;
  float* nrm;
  if (gw < N_IDE) {
    src = (const float4*)(ide + (size_t)gw * D_DIM);
    dst = (ushort4*)(Ah + (size_t)gw * D_DIM);
    nrm = x2 + gw;
  } else {
    int r = gw - N_IDE;
    src = (const float4*)(u + (size_t)r * D_DIM);
    dst = (ushort4*)(Bh + (size_t)r * D_DIM);
    nrm = y2 + r;
  }
  float4 v = src[l];
  float s = v.x * v.x + v.y * v.y + v.z * v.z + v.w * v.w;
  ushort4 o;
  o.x = f2h_bits(v.x); o.y = f2h_bits(v.y);
  o.z = f2h_bits(v.z); o.w = f2h_bits(v.w);
  dst[l] = o;
#pragma unroll
  for (int m = 1; m <= 32; m <<= 1) s += __shfl_xor(s, m, 64);
  if (l == 0) *nrm = s;
}

// ---- Kernel 2: occupancy-first MFMA GEMM (m97-shape: 3 blocks/CU) ----
// grid (32, 32): bx = 512-col group, by = 128-row group. 256 threads = 4 waves
// (2x2 grid, wave tile 64x64 -> acc[4][4] = 64 AGPR). Block does 4 serial
// col-rounds of 128 cols; per round 8 K-steps of BK=32, A+B double-buffered
// (33 KB LDS). __launch_bounds__(256,3) caps regs at ~170 incl AGPR ->
// 12 waves/CU = 3 co-resident blocks: one block's barrier/vmcnt drain is
// hidden by the other two blocks' MFMAs (the lever all r0-r5 variants
// lacked at 256 regs/wave = 1 block/CU).
// LDS tiles [128r x 4 slots x 8 f16], slot = kc ^ ((row>>1)&3): per-16-lane
// ds_read_b128 phase spreads over all 4 slots -> 2-way conflict (free).
__global__ __launch_bounds__(256, 3) void k_gemm(const unsigned short* __restrict__ Ah,
                                                 const unsigned short* __restrict__ Bh,
                                                 const float* __restrict__ x2,
                                                 const float* __restrict__ y2,
                                                 float* __restrict__ partial) {
  __shared__ __align__(16) unsigned short sA[2][4096];   // 8 KB per buf
  __shared__ __align__(16) unsigned short sB[2][4096];
  __shared__ float rowacc[2][128];                       // per-wn slices

  const int t    = threadIdx.x;
  const int w    = t >> 6;
  const int l    = t & 63;
  const int lrow = l & 15;
  const int lhi  = l >> 4;
  const int wm   = w >> 1, wn = w & 1;   // 2x2 wave grid; wave tile 64x64
  const int bx   = blockIdx.x;           // 0..31 (512 cols)
  const int by   = blockIdx.y;           // 0..31 (128 rows)

  rowacc[t >> 7][t & 127] = 0.f;

  // staging: chunk c = {t, 256+t}: row = c>>2, slot = c&3,
  // logical kc = slot ^ ((row>>1)&3)  (identical for both chunks: +64 rows)
  const int r0  = t >> 2;
  const int kc0 = (t & 3) ^ ((r0 >> 1) & 3);
  const size_t soff = (size_t)r0 * D_DIM + kc0 * 8;

  const unsigned short* Ab = Ah + (size_t)(by * 128) * D_DIM;

  // read-side swizzled slot (lane-const): rows are base16+lrow -> (row>>1)&3
  // == (lrow>>1)&3
  const int sl = (lhi ^ ((lrow >> 1) & 3)) * 8;

  for (int cr = 0; cr < 4; ++cr) {
    const unsigned short* Bb = Bh + (size_t)(bx * 512 + cr * 128) * D_DIM;

    auto stg = [&](int kt, int buf) {
      const unsigned short* sa = Ab + kt * 32 + soff;
      unsigned short* da = &sA[buf][w * 512];
      gll16(sa, da);
      gll16(sa + (size_t)64 * D_DIM, da + 2048);
      const unsigned short* sb = Bb + kt * 32 + soff;
      unsigned short* db = &sB[buf][w * 512];
      gll16(sb, db);
      gll16(sb + (size_t)64 * D_DIM, db + 2048);
    };

    f32x4 acc[4][4];
#pragma unroll
    for (int mi = 0; mi < 4; ++mi)
#pragma unroll
      for (int nj = 0; nj < 4; ++nj)
        acc[mi][nj] = (f32x4){0.f, 0.f, 0.f, 0.f};

    stg(0, 0);
    __syncthreads();                 // A0+B0 landed (barrier drains vmcnt)

    for (int kt = 0; kt < 8; ++kt) {
      if (kt < 7) stg(kt + 1, (kt + 1) & 1);   // prefetch into other buffer

      const unsigned short* pa = &sA[kt & 1][0];
      const unsigned short* pb = &sB[kt & 1][0];
      f16x8 af[4], bf[4];
#pragma unroll
      for (int mi = 0; mi < 4; ++mi)
        af[mi] = *(const f16x8*)(pa + (wm * 64 + mi * 16 + lrow) * 32 + sl);
#pragma unroll
      for (int nj = 0; nj < 4; ++nj)
        bf[nj] = *(const f16x8*)(pb + (wn * 64 + nj * 16 + lrow) * 32 + sl);

#pragma unroll
      for (int mi = 0; mi < 4; ++mi)
#pragma unroll
        for (int nj = 0; nj < 4; ++nj)
          acc[mi][nj] = __builtin_amdgcn_mfma_f32_16x16x32_f16(af[mi], bf[nj],
                                                               acc[mi][nj], 0, 0, 0);
      __syncthreads();               // prefetch drained; buffer swap safe
    }

    // ---- epilogue: dist + row partial sums into this wave's rowacc slice ----
    float yv[4];
#pragma unroll
    for (int nj = 0; nj < 4; ++nj)
      yv[nj] = y2[bx * 512 + cr * 128 + wn * 64 + nj * 16 + lrow];

#pragma unroll
    for (int mi = 0; mi < 4; ++mi) {
      float4 x2v = *(const float4*)&x2[by * 128 + wm * 64 + mi * 16 + lhi * 4];
      float xr[4] = {x2v.x, x2v.y, x2v.z, x2v.w};
#pragma unroll
      for (int rr = 0; rr < 4; ++rr) {
        float ssum = 0.f;
#pragma unroll
        for (int nj = 0; nj < 4; ++nj) {
          float d2 = xr[rr] + yv[nj] - 2.0f * acc[mi][nj][rr];
          d2 = fmaxf(d2, 0.0f);
          ssum += __builtin_amdgcn_sqrtf(d2 + EPSF);
        }
        ssum += __shfl_xor(ssum, 1, 64);
        ssum += __shfl_xor(ssum, 2, 64);
        ssum += __shfl_xor(ssum, 4, 64);
        ssum += __shfl_xor(ssum, 8, 64);
        if (lrow == 0)
          rowacc[wn][wm * 64 + mi * 16 + lhi * 4 + rr] += ssum;  // lane-private addr
      }
    }
  }

  __syncthreads();
  if (t < 128)
    partial[(size_t)(by * 128 + t) * 32 + bx] = rowacc[0][t] + rowacc[1][t];
}

// ---- Kernel 3: loss; in-block dsum reads partial[row][32] as 8 float4 ----
__global__ __launch_bounds__(256) void k_loss(const float* __restrict__ partial,
                                              float* __restrict__ out) {
  __shared__ float sd[N_IDE];
  __shared__ float wsum[4];
  int t = threadIdx.x;
  for (int k = t; k < N_IDE; k += 256) {
    const float4* p = (const float4*)(partial + (size_t)k * 32);
    float4 a = p[0];
#pragma unroll
    for (int b = 1; b < 8; ++b) {
      float4 q = p[b];
      a.x += q.x; a.y += q.y; a.z += q.z; a.w += q.w;
    }
    sd[k] = (a.x + a.y) + (a.z + a.w);   // same order every block
  }
  __syncthreads();
  int tid = blockIdx.x * 256 + t;   // 65536 threads: 16 per i
  int i   = tid >> 4;
  int jl  = tid & 15;
  float di = sd[i];
  float s  = 0.f;
  for (int k = 0; k < 256; ++k) {
    float diff = (di - sd[jl + k * 16]) * INV_M;
    s += __builtin_amdgcn_sqrtf(diff * diff + EPSF);
  }
#pragma unroll
  for (int m = 1; m <= 32; m <<= 1) s += __shfl_xor(s, m, 64);
  if ((t & 63) == 0) wsum[t >> 6] = s;
  __syncthreads();
  if (t == 0) atomicAdd(out, wsum[0] + wsum[1] + wsum[2] + wsum[3]);
}

extern "C" void kernel_launch(void* const* d_in, const int* in_sizes, int n_in,
                              void* d_out, int out_size, void* d_ws, size_t ws_size,
                              hipStream_t stream) {
  (void)in_sizes; (void)n_in; (void)out_size; (void)ws_size;
  const float* ide = (const float*)d_in[0];
  const float* u   = (const float*)d_in[1];
  float* out = (float*)d_out;

  char* ws = (char*)d_ws;
  size_t off = 0;
  unsigned short* Ah = (unsigned short*)(ws + off); off += (size_t)N_IDE * D_DIM * 2;  // 2 MB
  unsigned short* Bh = (unsigned short*)(ws + off); off += (size_t)M_U  * D_DIM * 2;   // 8 MB
  float* x2      = (float*)(ws + off); off += (size_t)N_IDE * 4;
  float* y2      = (float*)(ws + off); off += (size_t)M_U * 4;
  float* partial = (float*)(ws + off); off += (size_t)N_IDE * 32 * 4;                  // 512 KB

  k_conv<<<(N_IDE + M_U) / 4, 256, 0, stream>>>(ide, u, Ah, Bh, x2, y2, out);
  k_gemm<<<dim3(32, 32), 256, 0, stream>>>(Ah, Bh, x2, y2, partial);
  k_loss<<<256, 256, 0, stream>>>(partial, out);
}

// Round 9
// 124.377 us; speedup vs baseline: 1.2999x; 1.2999x over previous
//
#include <hip/hip_runtime.h>
#include <hip/hip_bf16.h>
#include <cstdint>

#define N_IDE 4096
#define M_U   16384
#define D_DIM 256
#define EPSF  1e-12f
#define INV_M (1.0f / 16384.0f)

#define CGC   512                 // columns per column-group tile
#define BK    32                  // K per step
#define SB_ELEMS (CGC * BK)       // 16384 f16 = 32 KB

typedef _Float16 f16x8 __attribute__((ext_vector_type(8)));
typedef float    f32x4 __attribute__((ext_vector_type(4)));

// ---- async global->LDS 16B copy. LDS dest = wave-uniform base + lane*16. ----
__device__ __forceinline__ void gll16(const void* g, void* l) {
  __builtin_amdgcn_global_load_lds(
      (const __attribute__((address_space(1))) void*)(uintptr_t)g,
      (__attribute__((address_space(3))) void*)(uint32_t)(uintptr_t)l,
      16, 0, 0);
}

__device__ __forceinline__ unsigned short f2h_bits(float f) {
  _Float16 h = (_Float16)f;
  return __builtin_bit_cast(unsigned short, h);
}

// ---- Kernel 1: fp32 -> f16 convert + row squared-norms (one wave per row) ----
__global__ __launch_bounds__(256) void k_conv(const float* __restrict__ ide,
                                              const float* __restrict__ u,
                                              unsigned short* __restrict__ Ah,
                                              unsigned short* __restrict__ Bh,
                                              float* __restrict__ x2,
                                              float* __restrict__ y2,
                                              float* __restrict__ out) {
  if (blockIdx.x == 0 && threadIdx.x == 0) out[0] = 0.f;   // replaces memset launch
  int gw = (blockIdx.x * 256 + threadIdx.x) >> 6;
  int l  = threadIdx.x & 63;
  const float4* src;
  ushort4* dst;
  float* nrm;
  if (gw < N_IDE) {
    src = (const float4*)(ide + (size_t)gw * D_DIM);
    dst = (ushort4*)(Ah + (size_t)gw * D_DIM);
    nrm = x2 + gw;
  } else {
    int r = gw - N_IDE;
    src = (const float4*)(u + (size_t)r * D_DIM);
    dst = (ushort4*)(Bh + (size_t)r * D_DIM);
    nrm = y2 + r;
  }
  float4 v = src[l];
  float s = v.x * v.x + v.y * v.y + v.z * v.z + v.w * v.w;
  ushort4 o;
  o.x = f2h_bits(v.x); o.y = f2h_bits(v.y);
  o.z = f2h_bits(v.z); o.w = f2h_bits(v.w);
  dst[l] = o;
#pragma unroll
  for (int m = 1; m <= 32; m <<= 1) s += __shfl_xor(s, m, 64);
  if (l == 0) *nrm = s;
}

// ---- Kernel 2: r0 persistent-A MFMA GEMM + B bank-conflict swizzle ----
// IDENTICAL to the 51.7us r0/r7 kernel except ONE change: B tile chunks are
// stored at slot c ^ ((row>>1)&3) (via pre-swizzled global source; LDS dest
// stays linear per global_load_lds), and fragment reads use the matching
// pchB = lhi ^ ((lrow>>1)&3). The natural 64B-pitch layout made each
// 16-lane ds_read_b128 phase hit banks {r*16 mod 32}: 8-way conflict,
// 6.0 cyc/read x 524288 reads = 3.15M cycles (12.3K/CU = ~5.1us measured
// every round on this structure). Swizzled: 8 banks x 2-way = free (m136).
__global__ __launch_bounds__(512, 2) void k_gemm(const unsigned short* __restrict__ Ah,
                                                 const unsigned short* __restrict__ Bh,
                                                 const float* __restrict__ x2,
                                                 const float* __restrict__ y2,
                                                 float* __restrict__ partial) {
  __shared__ __align__(16) unsigned short sA[128 * 256];      // 64 KB
  __shared__ __align__(16) unsigned short sB[2 * SB_ELEMS];   // 64 KB
  __shared__ float rowacc[4][128];                            // per-wn slices

  const int t    = threadIdx.x;
  const int w    = t >> 6;
  const int l    = t & 63;
  const int wm   = w >> 2, wn = w & 3;   // 2x4 wave grid; wave tile 64x128
  const int lrow = l & 15;
  const int lhi  = l >> 4;
  const int bx   = blockIdx.x;           // 0..7
  const int by   = blockIdx.y;           // 0..31

  rowacc[t >> 7][t & 127] = 0.f;         // 512 threads cover 4x128 exactly

  // ---- stage A (128 rows x 256 K), XOR-swizzled in 16B chunks ----
#pragma unroll
  for (int i = 0; i < 8; ++i) {
    int L = i * 512 + t;                 // chunk id 0..4095
    int row = L >> 5;
    int p = L & 31;
    int c = (p & 24) | ((p & 7) ^ (row & 7));
    gll16(Ah + (size_t)(by * 128 + row) * D_DIM + c * 8,
          sA + (size_t)(i * 512 + w * 64) * 8);
  }

  // ---- B tile stage: flat step s -> buf s&1; SOURCE pre-swizzled so LDS
  //      slot c holds global chunk c ^ ((row>>1)&3) (dest stays linear) ----
  auto stageB = [&](int s) {
    const int cgi = (s >> 3) * 8 + bx;   // column-group 0..31
    const int kt  = s & 7;
    const unsigned short* src = Bh + (size_t)cgi * CGC * D_DIM + kt * BK;
    unsigned short* dstb = sB + (size_t)(s & 1) * SB_ELEMS;
#pragma unroll
    for (int j = 0; j < 4; ++j) {
      int L = j * 512 + t;               // chunk id 0..2047
      int row = L >> 2;                  // B row (= C column) 0..511
      int c = (L & 3) ^ ((row >> 1) & 3);  // <- swizzled source chunk
      gll16(src + (size_t)row * D_DIM + c * 8,
            dstb + (size_t)(j * 512 + w * 64) * 8);
    }
  };

  // B read-side swizzled slot (lane-const): brow = 16k + lrow -> (brow>>1)&3
  // == (lrow>>1)&3
  const int pchB = lhi ^ ((lrow >> 1) & 3);

  // x2 for this wave's rows, loaded once (rr 0..3 contiguous -> float4)
  float4 x2v[4];
#pragma unroll
  for (int mi = 0; mi < 4; ++mi)
    x2v[mi] = *(const float4*)&x2[by * 128 + wm * 64 + mi * 16 + lhi * 4];

  stageB(0);
  __syncthreads();    // barrier drains vmcnt(0): A + B(step 0) ready

  for (int cg = 0; cg < 4; ++cg) {
    const int cgi = cg * 8 + bx;

    f32x4 acc[4][8];
#pragma unroll
    for (int mi = 0; mi < 4; ++mi)
#pragma unroll
      for (int ni = 0; ni < 8; ++ni)
        acc[mi][ni] = (f32x4){0.f, 0.f, 0.f, 0.f};

    for (int kt = 0; kt < 8; ++kt) {
      const int s = cg * 8 + kt;
      if (s + 1 < 32) stageB(s + 1);     // prefetch into other buffer

      // A fragments: logical chunk kt*4+lhi, physical = swizzled
      f16x8 af[4];
#pragma unroll
      for (int mi = 0; mi < 4; ++mi) {
        int arow = wm * 64 + mi * 16 + lrow;
        int lc   = kt * 4 + lhi;
        int pc   = (lc & 24) | ((lc & 7) ^ (lrow & 7));
        af[mi] = *(const f16x8*)(sA + (size_t)arow * 256 + pc * 8);
      }

      const unsigned short* bbuf = sB + (size_t)(s & 1) * SB_ELEMS;
#pragma unroll
      for (int half = 0; half < 2; ++half) {
        f16x8 bf[4];
#pragma unroll
        for (int nj = 0; nj < 4; ++nj) {
          int brow = wn * 128 + (half * 4 + nj) * 16 + lrow;
          bf[nj] = *(const f16x8*)(bbuf + (size_t)brow * BK + pchB * 8);
        }
#pragma unroll
        for (int mi = 0; mi < 4; ++mi)
#pragma unroll
          for (int nj = 0; nj < 4; ++nj)
            acc[mi][half * 4 + nj] =
                __builtin_amdgcn_mfma_f32_16x16x32_f16(af[mi], bf[nj],
                                                       acc[mi][half * 4 + nj], 0, 0, 0);
      }
      __syncthreads();   // prefetch drained; buffer swap safe
    }

    // ---- epilogue: dist + row partial sums into this wave's rowacc slice ----
    float yv[8];
#pragma unroll
    for (int ni = 0; ni < 8; ++ni)
      yv[ni] = y2[cgi * CGC + wn * 128 + ni * 16 + lrow];

#pragma unroll
    for (int mi = 0; mi < 4; ++mi) {
      float xr[4] = {x2v[mi].x, x2v[mi].y, x2v[mi].z, x2v[mi].w};
#pragma unroll
      for (int rr = 0; rr < 4; ++rr) {
        float ssum = 0.f;
#pragma unroll
        for (int ni = 0; ni < 8; ++ni) {
          float d2 = xr[rr] + yv[ni] - 2.0f * acc[mi][ni][rr];
          d2 = fmaxf(d2, 0.0f);
          ssum += __builtin_amdgcn_sqrtf(d2 + EPSF);
        }
        ssum += __shfl_xor(ssum, 1, 64);
        ssum += __shfl_xor(ssum, 2, 64);
        ssum += __shfl_xor(ssum, 4, 64);
        ssum += __shfl_xor(ssum, 8, 64);
        if (lrow == 0)
          rowacc[wn][wm * 64 + mi * 16 + lhi * 4 + rr] += ssum;  // wave-private slice
      }
    }
  }

  __syncthreads();
  if (t < 128)
    partial[(size_t)bx * N_IDE + by * 128 + t] =
        rowacc[0][t] + rowacc[1][t] + rowacc[2][t] + rowacc[3][t];
}

// ---- Kernel 3: loss = sum_{i,j} sqrt(((d_i-d_j))^2 + eps), d from partials ----
__global__ __launch_bounds__(256) void k_loss(const float* __restrict__ partial,
                                              float* __restrict__ out) {
  __shared__ float sd[N_IDE];
  __shared__ float wsum[4];
  int t = threadIdx.x;
  for (int k = t; k < N_IDE; k += 256) {
    float s = 0.f;
#pragma unroll
    for (int b = 0; b < 8; ++b) s += partial[(size_t)b * N_IDE + k];
    sd[k] = s;
  }
  __syncthreads();
  int tid = blockIdx.x * 256 + t;   // 65536 threads: 16 per i
  int i   = tid >> 4;
  int jl  = tid & 15;
  float di = sd[i];
  float s  = 0.f;
  for (int k = 0; k < 256; ++k) {
    float diff = (di - sd[jl + k * 16]) * INV_M;
    s += __builtin_amdgcn_sqrtf(diff * diff + EPSF);
  }
#pragma unroll
  for (int m = 1; m <= 32; m <<= 1) s += __shfl_xor(s, m, 64);
  if ((t & 63) == 0) wsum[t >> 6] = s;
  __syncthreads();
  if (t == 0) atomicAdd(out, wsum[0] + wsum[1] + wsum[2] + wsum[3]);
}

extern "C" void kernel_launch(void* const* d_in, const int* in_sizes, int n_in,
                              void* d_out, int out_size, void* d_ws, size_t ws_size,
                              hipStream_t stream) {
  (void)in_sizes; (void)n_in; (void)out_size; (void)ws_size;
  const float* ide = (const float*)d_in[0];
  const float* u   = (const float*)d_in[1];
  float* out = (float*)d_out;

  char* ws = (char*)d_ws;
  size_t off = 0;
  unsigned short* Ah = (unsigned short*)(ws + off); off += (size_t)N_IDE * D_DIM * 2;  // 2 MB
  unsigned short* Bh = (unsigned short*)(ws + off); off += (size_t)M_U  * D_DIM * 2;   // 8 MB
  float* x2      = (float*)(ws + off); off += (size_t)N_IDE * 4;
  float* y2      = (float*)(ws + off); off += (size_t)M_U * 4;
  float* partial = (float*)(ws + off); off += (size_t)8 * N_IDE * 4;                   // 128 KB

  k_conv<<<(N_IDE + M_U) / 4, 256, 0, stream>>>(ide, u, Ah, Bh, x2, y2, out);
  k_gemm<<<dim3(8, 32), 512, 0, stream>>>(Ah, Bh, x2, y2, partial);
  k_loss<<<256, 256, 0, stream>>>(partial, out);
}